// Round 6
// baseline (45.067 us; speedup 1.0000x reference)
//
#include <hip/hip_runtime.h>
#include <hip/hip_cooperative_groups.h>
#include <math.h>

namespace cg = cooperative_groups;

// ComparingLoss: s = sum_{i<j, disc(i,j)} (d_i + d_j), out = s/T
// s = sum_i d_i * c_i, canonical predicate (xi>xj)^(li>lj) over ALL j
// (valid both orientations for tie-free data; false at j==i).
//
// R6: ONE cooperative kernel. 256 blocks x 1024 threads (16 waves/CU).
// Each block writes its partial (plain store, no init needed), grid.sync()
// (runtime-initialized barrier -> no memset node, no DIY atomic counter),
// then block 0 wave 0 reduces 256 partials and writes out[0].

#define T_N  8192
#define BLK  1024                // threads per block
#define IPT  4                   // consecutive i-rows per thread
#define JC   64                  // j-chunk per block
#define NIB  (T_N / (BLK * IPT)) // 2 i-blocks
#define NJC  (T_N / JC)          // 128 j-chunks
#define NBLK (NIB * NJC)         // 256 blocks

__global__ __launch_bounds__(BLK) void pair_coop_kernel(
    const float* __restrict__ x, const float* __restrict__ lab,
    float* __restrict__ partial, float* __restrict__ out) {
  cg::grid_group grid = cg::this_grid();
  __shared__ float2 js[JC];
  __shared__ float wsum[BLK / 64];

  const int tid = threadIdx.x;
  const int i0 = blockIdx.x * (BLK * IPT) + tid * IPT;  // 4 consecutive rows
  const int j0 = blockIdx.y * JC;

  if (tid < JC) js[tid] = make_float2(x[j0 + tid], lab[j0 + tid]);

  const float4 xv = *(const float4*)&x[i0];   // 16B coalesced
  const float4 lv = *(const float4*)&lab[i0];
  __syncthreads();

  int c0 = 0, c1 = 0, c2 = 0, c3 = 0;
#pragma unroll 16
  for (int jj = 0; jj < JC; ++jj) {
    const float2 v = js[jj];  // broadcast ds_read_b64, conflict-free
    c0 += (int)((xv.x > v.x) != (lv.x > v.y));
    c1 += (int)((xv.y > v.x) != (lv.y > v.y));
    c2 += (int)((xv.z > v.x) != (lv.z > v.y));
    c3 += (int)((xv.w > v.x) != (lv.w > v.y));
  }

  float val = fabsf(xv.x - lv.x) * (float)c0 + fabsf(xv.y - lv.y) * (float)c1 +
              fabsf(xv.z - lv.z) * (float)c2 + fabsf(xv.w - lv.w) * (float)c3;

  // wave-64 tree reduce
#pragma unroll
  for (int off = 32; off >= 1; off >>= 1) val += __shfl_down(val, off, 64);

  if ((tid & 63) == 0) wsum[tid >> 6] = val;
  __syncthreads();

  if (tid < 64) {
    float s = (tid < BLK / 64) ? wsum[tid] : 0.f;
#pragma unroll
    for (int off = 8; off >= 1; off >>= 1) s += __shfl_down(s, off, 64);
    if (tid == 0) partial[blockIdx.y * NIB + blockIdx.x] = s;
  }

  grid.sync();

  if (blockIdx.x == 0 && blockIdx.y == 0 && tid < NBLK / 4) {
    const float4 p = ((const float4*)partial)[tid];  // 64 lanes x 4 = 256
    double t = (double)p.x + (double)p.y + (double)p.z + (double)p.w;
#pragma unroll
    for (int off = 32; off >= 1; off >>= 1) t += __shfl_down(t, off, 64);
    if (tid == 0) out[0] = (float)(t / (double)T_N);
  }
}

extern "C" void kernel_launch(void* const* d_in, const int* in_sizes, int n_in,
                              void* d_out, int out_size, void* d_ws, size_t ws_size,
                              hipStream_t stream) {
  const float* x = (const float*)d_in[0];
  const float* lab = (const float*)d_in[1];
  float* out = (float*)d_out;
  float* partial = (float*)d_ws;  // NBLK floats = 1 KiB

  dim3 grid(NIB, NJC);
  dim3 block(BLK);
  void* args[] = {(void*)&x, (void*)&lab, (void*)&partial, (void*)&out};
  hipLaunchCooperativeKernel((const void*)pair_coop_kernel, grid, block,
                             args, 0, stream);
}

// Round 7
// 14.790 us; speedup vs baseline: 3.0471x; 3.0471x over previous
//
#include <hip/hip_runtime.h>
#include <math.h>

// ComparingLoss: s = sum_{i<j, disc(i,j)} (d_i + d_j), out = s/T
// s = sum_i d_i * c_i, canonical predicate (xi>xj)^(li>lj) over ALL j
// (valid both orientations for tie-free data; false at j==i).
//
// R7: back to the proven 2-kernel structure (best finish per R3/R5/R6
// structure calibration). Pair kernel: IPT=8 rows/thread so one broadcast
// ds_read_b64 serves 8 predicates -> DS drops under the 2.6us VALU floor.
// 1024 blocks (4/CU). Reduce: one wave, 4 independent float4 loads/lane.

#define T_N   8192
#define BLK   256                  // threads per block
#define IPT   8                    // consecutive i-rows per thread
#define JC    32                   // j-chunk per block
#define NIB   (T_N / (BLK * IPT))  // 4 i-blocks
#define NJC   (T_N / JC)           // 256 j-chunks
#define NPART (NIB * NJC)          // 1024 partials

__global__ __launch_bounds__(BLK) void pair_count_kernel(
    const float* __restrict__ x, const float* __restrict__ lab,
    float* __restrict__ partial) {
  __shared__ float2 js[JC];
  __shared__ float wsum[BLK / 64];

  const int tid = threadIdx.x;
  const int i0 = blockIdx.x * (BLK * IPT) + tid * IPT;  // 8 consecutive rows
  const int j0 = blockIdx.y * JC;

  if (tid < JC) js[tid] = make_float2(x[j0 + tid], lab[j0 + tid]);

  // 8 rows as 2x float4 (32B-aligned)
  const float4 xa = ((const float4*)&x[i0])[0];
  const float4 xb = ((const float4*)&x[i0])[1];
  const float4 la = ((const float4*)&lab[i0])[0];
  const float4 lb = ((const float4*)&lab[i0])[1];
  const float xi[IPT] = {xa.x, xa.y, xa.z, xa.w, xb.x, xb.y, xb.z, xb.w};
  const float li[IPT] = {la.x, la.y, la.z, la.w, lb.x, lb.y, lb.z, lb.w};
  __syncthreads();

  int cnt[IPT] = {0, 0, 0, 0, 0, 0, 0, 0};
#pragma unroll 8
  for (int jj = 0; jj < JC; ++jj) {
    const float2 v = js[jj];  // broadcast ds_read_b64, conflict-free
#pragma unroll
    for (int k = 0; k < IPT; ++k)
      cnt[k] += (int)((xi[k] > v.x) != (li[k] > v.y));
  }

  float val = 0.f;
#pragma unroll
  for (int k = 0; k < IPT; ++k)
    val += fabsf(xi[k] - li[k]) * (float)cnt[k];

  // wave-64 tree reduce
#pragma unroll
  for (int off = 32; off >= 1; off >>= 1) val += __shfl_down(val, off, 64);

  if ((tid & 63) == 0) wsum[tid >> 6] = val;
  __syncthreads();

  if (tid == 0) {
    const float s = wsum[0] + wsum[1] + wsum[2] + wsum[3];
    partial[blockIdx.y * NIB + blockIdx.x] = s;
  }
}

__global__ __launch_bounds__(64) void reduce_kernel(
    const float* __restrict__ partial, float* __restrict__ out) {
  const int tid = threadIdx.x;  // one wave, no __syncthreads needed
  // 4 independent float4 loads per lane cover 1024 partials
  const float4 p0 = ((const float4*)partial)[tid];
  const float4 p1 = ((const float4*)partial)[tid + 64];
  const float4 p2 = ((const float4*)partial)[tid + 128];
  const float4 p3 = ((const float4*)partial)[tid + 192];
  double s = ((double)p0.x + (double)p0.y + (double)p0.z + (double)p0.w) +
             ((double)p1.x + (double)p1.y + (double)p1.z + (double)p1.w) +
             ((double)p2.x + (double)p2.y + (double)p2.z + (double)p2.w) +
             ((double)p3.x + (double)p3.y + (double)p3.z + (double)p3.w);
#pragma unroll
  for (int off = 32; off >= 1; off >>= 1) s += __shfl_down(s, off, 64);
  if (tid == 0) out[0] = (float)(s / (double)T_N);
}

extern "C" void kernel_launch(void* const* d_in, const int* in_sizes, int n_in,
                              void* d_out, int out_size, void* d_ws, size_t ws_size,
                              hipStream_t stream) {
  const float* x = (const float*)d_in[0];
  const float* lab = (const float*)d_in[1];
  float* out = (float*)d_out;
  float* partial = (float*)d_ws;  // NPART floats = 4 KiB

  dim3 grid(NIB, NJC);
  pair_count_kernel<<<grid, BLK, 0, stream>>>(x, lab, partial);
  reduce_kernel<<<1, 64, 0, stream>>>(partial, out);
}